// Round 9
// baseline (20959.271 us; speedup 1.0000x reference)
//
#include <hip/hip_runtime.h>
#include <hip/hip_fp16.h>
#include <hip/hip_cooperative_groups.h>

namespace cg = cooperative_groups;

#define T_SEQ 4096
#define D_IN  512
#define D_H   2048
#define D_C   2560
#define D_OUT 512
#define NBLK  256      // 248 compute + 8 pure relay (one per XCD by dispatch round-robin)
#define NCOMP 248
#define NTHR  512
#define SPIN_CAP 4096

typedef unsigned int u32;
typedef u32 u32x4 __attribute__((ext_vector_type(4)));

__device__ __forceinline__ void dot4(float& acc, const float4& a, const float4& b) {
    acc = fmaf(a.x, b.x, acc);
    acc = fmaf(a.y, b.y, acc);
    acc = fmaf(a.z, b.z, acc);
    acc = fmaf(a.w, b.w, acc);
}

// DPP wave64 sum -> lane 63
template<int CTRL, int RMASK>
__device__ __forceinline__ float dpp_add(float x) {
    int t = __builtin_amdgcn_update_dpp(0, __float_as_int(x), CTRL, RMASK, 0xf, true);
    return x + __int_as_float(t);
}
__device__ __forceinline__ float wave_red63(float x) {
    x = dpp_add<0x111, 0xf>(x);
    x = dpp_add<0x112, 0xf>(x);
    x = dpp_add<0x114, 0xf>(x);
    x = dpp_add<0x118, 0xf>(x);
    x = dpp_add<0x142, 0xa>(x);
    x = dpp_add<0x143, 0xc>(x);
    return x;
}

__device__ __forceinline__ float fast_sigmoid(float z) {
    float e = __builtin_amdgcn_exp2f(-1.44269504f * z);
    return __builtin_amdgcn_rcpf(1.0f + e);
}
__device__ __forceinline__ float fast_tanh(float z) {
    float e2 = __builtin_amdgcn_exp2f(2.88539008f * z);
    return 1.0f - 2.0f * __builtin_amdgcn_rcpf(e2 + 1.0f);
}

// AGPR pinning (R5-proven): h-weights live in the accumulator file.
#define AW(i, v) asm volatile("v_accvgpr_write_b32 %0, %1" : "=a"(aw[i]) : "v"(v))
#define AR(d, i) asm volatile("v_accvgpr_read_b32 %0, %1" : "=v"(d) : "a"(aw[i]))
#define DOT4A(acc, base, hv) do { float4 _w;                          \
        AR(_w.x, (base) + 0); AR(_w.y, (base) + 1);                   \
        AR(_w.z, (base) + 2); AR(_w.w, (base) + 3);                   \
        dot4(acc, _w, hv); } while (0)

// ---- exchange fabric primitives (R8-proven) ----
__device__ __forceinline__ u32x4 load_quad_l3(const u32* p) {   // coherence point
    u32x4 v;
    asm volatile("global_load_dwordx4 %0, %1, off sc0 sc1\n\ts_waitcnt vmcnt(0)"
                 : "=&v"(v) : "v"(p) : "memory");
    return v;
}
__device__ __forceinline__ u32x4 load_quad_l2(const u32* p) {   // local-L2 (bypass L1)
    u32x4 v;
    asm volatile("global_load_dwordx4 %0, %1, off sc0\n\ts_waitcnt vmcnt(0)"
                 : "=&v"(v) : "v"(p) : "memory");
    return v;
}
__device__ __forceinline__ void store_quad_l2(u32* p, u32x4 v) {
    asm volatile("global_store_dwordx4 %0, %1, off" :: "v"(p), "v"(v) : "memory");
}
__device__ __forceinline__ bool tags_ok(u32x4 v, u32 tg) {
    return (v.x >> 16) == tg && (v.y >> 16) == tg &&
           (v.z >> 16) == tg && (v.w >> 16) == tg;
}
__device__ __forceinline__ float4 unpackq(u32x4 v) {
    return make_float4(
        __half2float(__ushort_as_half((unsigned short)(v.x & 0xFFFFu))),
        __half2float(__ushort_as_half((unsigned short)(v.y & 0xFFFFu))),
        __half2float(__ushort_as_half((unsigned short)(v.z & 0xFFFFu))),
        __half2float(__ushort_as_half((unsigned short)(v.w & 0xFFFFu))));
}
__device__ __forceinline__ u32 packh(int tag, float h) {
    return ((u32)(tag & 0xFFFF) << 16) | (u32)__half_as_ushort(__float2half(h));
}

__global__ __launch_bounds__(NTHR, 2) void lstm_persist(
    const float* __restrict__ x,         // [T_SEQ, D_IN]
    const float* __restrict__ hidden_in, // [D_H] (passthrough output)
    const float* __restrict__ Wi, const float* __restrict__ bi,
    const float* __restrict__ Wg, const float* __restrict__ bg,
    const float* __restrict__ Wo, const float* __restrict__ bo,
    const float* __restrict__ Wout, const float* __restrict__ bout,
    float* __restrict__ out,             // [D_OUT + D_H]
    u32* __restrict__ ws)                // hb2[2][D_H] + mirror[8][2][D_H]
{
    cg::grid_group grid = cg::this_grid();
    const int b    = blockIdx.x;
    const int tid  = threadIdx.x;
    const int lane = tid & 63;
    const int w    = tid >> 6;               // wave 0..7
    const int kb   = lane * 4;

    u32* hb2    = ws;                        // [2][D_H] packed (tag16|f16)
    u32* mirror = ws + 2 * D_H;              // [8][2][D_H]

    __shared__ float lds_h[D_H];
    __shared__ float part9[3][8];

    // ---- init (ws poisoned 0xAA). tag0|f16(0)==0: slot0 "h_0=0 valid".
    if (b == 0) {
        for (int i = tid; i < 2 * D_H + 16 * D_H; i += NTHR)
            __hip_atomic_store(&ws[i], 0u, __ATOMIC_RELAXED, __HIP_MEMORY_SCOPE_AGENT);
    }
    grid.sync();   // the only grid sync

    unsigned xcd;
    asm volatile("s_getreg_b32 %0, hwreg(HW_REG_XCC_ID)" : "=s"(xcd));
    xcd &= 7u;

    // ================= PURE RELAY BLOCKS (no compute, no barriers) =========
    if (b >= NCOMP) {
        u32* mpb = mirror + (size_t)xcd * 2 * D_H;
#pragma unroll 1
        for (int t = 1; t <= T_SEQ; ++t) {
            const u32 tg = (u32)t & 0xFFFFu;
            const u32* gp = hb2 + (t & 1) * D_H + tid * 4;
            u32*       mp = mpb + (t & 1) * D_H + tid * 4;
            u32x4 v;
            for (;;) { v = load_quad_l3(gp); if (tags_ok(v, tg)) break; }
            store_quad_l2(mp, v);
        }
        return;
    }

    // ================= COMPUTE BLOCKS ======================================
    // unit map: blocks 0..63 own 9 units, blocks 64..247 own 8. covers 0..2047.
    const bool nb9 = (b < 64);
    const int  ub  = nb9 ? b * 9 : 576 + (b - 64) * 8;
    const int  j   = ub + w;         // this wave's unit
    const int  j9  = ub + 8;         // 9th unit (nb9 only)

    // ---- pin h-part weight rows in AGPRs: 3 gates x 8 float4 = 96 floats.
    float aw[96];
    float4 wxi0, wxi1, wxg0, wxg1, wxo0, wxo1;
    {
        const size_t rh = (size_t)j * D_C + 512 + kb;
#pragma unroll
        for (int r = 0; r < 8; ++r) {
            const float4 vi = *(const float4*)(Wi + rh + 256 * r);
            const float4 vg = *(const float4*)(Wg + rh + 256 * r);
            const float4 vo = *(const float4*)(Wo + rh + 256 * r);
            AW(r * 4 + 0, vi.x); AW(r * 4 + 1, vi.y);
            AW(r * 4 + 2, vi.z); AW(r * 4 + 3, vi.w);
            AW(32 + r * 4 + 0, vg.x); AW(32 + r * 4 + 1, vg.y);
            AW(32 + r * 4 + 2, vg.z); AW(32 + r * 4 + 3, vg.w);
            AW(64 + r * 4 + 0, vo.x); AW(64 + r * 4 + 1, vo.y);
            AW(64 + r * 4 + 2, vo.z); AW(64 + r * 4 + 3, vo.w);
        }
        const size_t ro = (size_t)j * D_C + kb;
        wxi0 = *(const float4*)(Wi + ro); wxi1 = *(const float4*)(Wi + ro + 256);
        wxg0 = *(const float4*)(Wg + ro); wxg1 = *(const float4*)(Wg + ro + 256);
        wxo0 = *(const float4*)(Wo + ro); wxo1 = *(const float4*)(Wo + ro + 256);
    }
    const float b_i = bi[j];
    const float b_g = bg[j];
    const float b_o = bo[j];
    float b9i = 0.f, b9g = 0.f, b9o = 0.f;
    if (nb9) { b9i = bi[j9]; b9g = bg[j9]; b9o = bo[j9]; }

    float4 xv0 = *(const float4*)(x + kb);
    float4 xv1 = *(const float4*)(x + kb + 256);

    int use_l2 = 1;

#pragma unroll 1
    for (int t = 0; t < T_SEQ; ++t) {
        // ---- x-part of gate dots + prefetches (before the poll)
        float ai = 0.f, ag = 0.f, ao = 0.f;
        dot4(ai, wxi0, xv0); dot4(ai, wxi1, xv1);
        dot4(ag, wxg0, xv0); dot4(ag, wxg1, xv1);
        dot4(ao, wxo0, xv0); dot4(ao, wxo1, xv1);
        const int tn = (t + 1 < T_SEQ) ? t + 1 : t;
        const float4 xn0 = *(const float4*)(x + (size_t)tn * D_IN + kb);
        const float4 xn1 = *(const float4*)(x + (size_t)tn * D_IN + kb + 256);

        // unit9 weights: reloaded each step (L1/L2-hot) to save VGPRs
        float4 w9i, w9g, w9o, x9i0, x9i1, x9g0, x9g1, x9o0, x9o1;
        if (nb9) {
            const size_t r9 = (size_t)j9 * D_C;
            w9i = *(const float4*)(Wi + r9 + 512 + w * 256 + kb);
            w9g = *(const float4*)(Wg + r9 + 512 + w * 256 + kb);
            w9o = *(const float4*)(Wo + r9 + 512 + w * 256 + kb);
            if (w == 0) {
                x9i0 = *(const float4*)(Wi + r9 + kb); x9i1 = *(const float4*)(Wi + r9 + kb + 256);
                x9g0 = *(const float4*)(Wg + r9 + kb); x9g1 = *(const float4*)(Wg + r9 + kb + 256);
                x9o0 = *(const float4*)(Wo + r9 + kb); x9o1 = *(const float4*)(Wo + r9 + kb + 256);
            }
        }

        // ---- poll local-XCD mirror (L2 latency); latched L3 fallback
        const u32 tg = (u32)t & 0xFFFFu;
        const u32* gp = hb2 + (t & 1) * D_H + tid * 4;
        const u32* mp = mirror + ((size_t)xcd * 2 + (t & 1)) * D_H + tid * 4;
        u32x4 v;
        bool got = false;
        if (use_l2) {
            for (int s = 0; s < SPIN_CAP; ++s) {
                v = load_quad_l2(mp);
                if (tags_ok(v, tg)) { got = true; break; }
            }
            if (!got) use_l2 = 0;
        }
        if (!got) {
            for (;;) { v = load_quad_l3(gp); if (tags_ok(v, tg)) break; }
        }
        *(float4*)(&lds_h[tid * 4]) = unpackq(v);
        __syncthreads();   // sync #1

        // ---- h-part: 8 rows x 3 gates, weights from AGPRs
#pragma unroll
        for (int r = 0; r < 8; ++r) {
            const float4 hv = *(const float4*)(&lds_h[r * 256 + kb]);
            DOT4A(ai, r * 4, hv);
            DOT4A(ag, 32 + r * 4, hv);
            DOT4A(ao, 64 + r * 4, hv);
        }

        ai = wave_red63(ai); ag = wave_red63(ag); ao = wave_red63(ao);

        if (lane == 63) {   // publish this wave's unit ASAP
            const float zi = ai + b_i;
            const float zg = ag + b_g;
            const float zo = ao + b_o;
            const float it = fast_sigmoid(zi);
            const float gt = fast_tanh(zg);
            const float ot = fast_sigmoid(zo);
            const float h  = ot * fast_tanh(it * gt);
            __hip_atomic_store(&hb2[((t + 1) & 1) * D_H + j], packh(t + 1, h),
                               __ATOMIC_RELAXED, __HIP_MEMORY_SCOPE_AGENT);
        }

        // ---- unit9: each wave contributes its 256-slice, wave0 combines
        if (nb9) {
            float p9i = 0.f, p9g = 0.f, p9o = 0.f;
            const float4 hv = *(const float4*)(&lds_h[w * 256 + kb]);
            dot4(p9i, w9i, hv); dot4(p9g, w9g, hv); dot4(p9o, w9o, hv);
            if (w == 0) {
                dot4(p9i, x9i0, xv0); dot4(p9i, x9i1, xv1);
                dot4(p9g, x9g0, xv0); dot4(p9g, x9g1, xv1);
                dot4(p9o, x9o0, xv0); dot4(p9o, x9o1, xv1);
            }
            p9i = wave_red63(p9i); p9g = wave_red63(p9g); p9o = wave_red63(p9o);
            if (lane == 63) { part9[0][w] = p9i; part9[1][w] = p9g; part9[2][w] = p9o; }
            __syncthreads();   // sync #2 (nb9 blocks only)
            if (w == 0) {
                float pv = (lane < 24) ? part9[lane >> 3][lane & 7] : 0.f;
                pv += __shfl_xor(pv, 1, 64);
                pv += __shfl_xor(pv, 2, 64);
                pv += __shfl_xor(pv, 4, 64);
                const float zi = __shfl(pv, 0, 64)  + b9i;
                const float zg = __shfl(pv, 8, 64)  + b9g;
                const float zo = __shfl(pv, 16, 64) + b9o;
                const float it = fast_sigmoid(zi);
                const float gt = fast_tanh(zg);
                const float ot = fast_sigmoid(zo);
                const float h  = ot * fast_tanh(it * gt);
                if (lane == 0)
                    __hip_atomic_store(&hb2[((t + 1) & 1) * D_H + j9], packh(t + 1, h),
                                       __ATOMIC_RELAXED, __HIP_MEMORY_SCOPE_AGENT);
            }
        }

        xv0 = xn0; xv1 = xn1;
    }

    // ---- epilogue
    if (b < 64) {
        const u32 tg = (u32)T_SEQ & 0xFFFFu;
        const u32* gp = hb2 + tid * 4;                       // slot 0 (T_SEQ even)
        const u32* mp = mirror + ((size_t)xcd * 2) * D_H + tid * 4;
        u32x4 v;
        bool got = false;
        if (use_l2) {
            for (int s = 0; s < SPIN_CAP; ++s) {
                v = load_quad_l2(mp);
                if (tags_ok(v, tg)) { got = true; break; }
            }
        }
        if (!got) {
            for (;;) { v = load_quad_l3(gp); if (tags_ok(v, tg)) break; }
        }
        *(float4*)(&lds_h[tid * 4]) = unpackq(v);
        __syncthreads();

        const int ow = b * 8 + w;                            // 64 blocks x 8 = 512 rows
        const float* pw = Wout + (size_t)ow * D_H + kb;
        float acc = 0.f;
#pragma unroll
        for (int r = 0; r < 8; ++r) {
            const float4 w4 = *(const float4*)(pw + 256 * r);
            const float4 hv = *(const float4*)(&lds_h[kb + 256 * r]);
            dot4(acc, w4, hv);
        }
        acc = wave_red63(acc);
        if (lane == 63) out[ow] = acc + bout[ow];
    } else if (b >= 64 && b < 66) {
        const int base = (b - 64) * 1024;
        out[D_OUT + base + tid]       = hidden_in[base + tid];
        out[D_OUT + base + tid + 512] = hidden_in[base + tid + 512];
    }
}

extern "C" void kernel_launch(void* const* d_in, const int* in_sizes, int n_in,
                              void* d_out, int out_size, void* d_ws, size_t ws_size,
                              hipStream_t stream) {
    const float* x      = (const float*)d_in[0];
    const float* hidden = (const float*)d_in[1];
    const float* Wi     = (const float*)d_in[2];
    const float* bi     = (const float*)d_in[3];
    const float* Wg     = (const float*)d_in[4];
    const float* bg     = (const float*)d_in[5];
    const float* Wo     = (const float*)d_in[6];
    const float* bo     = (const float*)d_in[7];
    const float* Wout   = (const float*)d_in[8];
    const float* bout   = (const float*)d_in[9];
    float* out = (float*)d_out;
    u32* ws = (u32*)d_ws;   // 16 KB hb2 + 128 KB mirrors

    void* args[] = {(void*)&x, (void*)&hidden, (void*)&Wi, (void*)&bi,
                    (void*)&Wg, (void*)&bg, (void*)&Wo, (void*)&bo,
                    (void*)&Wout, (void*)&bout, (void*)&out, (void*)&ws};
    (void)hipLaunchCooperativeKernel((const void*)lstm_persist,
                                     dim3(NBLK), dim3(NTHR), args, 0, stream);
}